// Round 1
// baseline (365.236 us; speedup 1.0000x reference)
//
#include <hip/hip_runtime.h>
#include <hip/hip_bf16.h>
#include <cstddef>

// Problem constants (fixed-shape problem)
constexpr int N_NODES = 50000;
constexpr int N_EDGES = 800000;
constexpr int IN_DIM  = 128;
constexpr int HID     = 64;
constexpr int HEADS   = 4;
constexpr int F1      = HEADS * HID;  // 256
constexpr int EMB     = 128;
constexpr int N_GRAPHS = 64;

constexpr int DEG_BLOCKS   = (N_EDGES + 255) / 256;          // 3125
constexpr int SCAN_BLOCKS  = (N_NODES + 255) / 256;          // 196
constexpr int GEMM1_BLOCKS = (N_NODES + 63) / 64;            // 782
constexpr int XCONV_BLOCKS = (N_NODES * IN_DIM / 4) / 256;   // 6250 (exact)
// per-head W1 fragment size (NT=4, KK=4): 4*4*64*8 bf16 elements
constexpr int W1_FRAG = 4 * 4 * 64 * 8;                      // 8192
// gemm12 LDS tile stride in bf16 elems: 264*2 = 528 B rows (16 B aligned for
// ds_read_b128; 132 dwords mod 32 = 4 -> ~2-way bank alias, free per m136)
constexpr int LDSB = 264;
// bucketed CSR build: 256-node buckets; pass-1 appends packed (s|d<<16)
// records per bucket (dense runs -> L2 write combining), pass-2 distributes
// within the bucket's small col/w4 windows (L2-hot lines). This replaces the
// former fully-random 4B col scatter whose 64B-line amplification was 51 MB
// of the 57 MB WRITE_SIZE on the gemm1_scatter dispatch.
constexpr int NBUCK    = (N_NODES + 255) / 256;              // 196
constexpr int P1_CHUNK = 8192;                               // edges per pass-1 block
constexpr int P1_BLOCKS = (N_EDGES + P1_CHUNK - 1) / P1_CHUNK; // 98

typedef __bf16 bf16x8 __attribute__((ext_vector_type(8)));
typedef __bf16 bf16x2 __attribute__((ext_vector_type(2)));
typedef float  f32x4  __attribute__((ext_vector_type(4)));

__device__ __forceinline__ float lrelu(float x) { return x > 0.f ? x : 0.2f * x; }
__device__ __forceinline__ float eluf(float x)  { return x > 0.f ? x : expm1f(x); }

// ---------------------------------------------------------------------------
// Pack a [K x 16*NT] submatrix of B (leading dim ld, origin col0) into
// per-lane MFMA B-fragments, split hi/lo bf16.
// ---------------------------------------------------------------------------
__device__ __forceinline__ void pack_frag(const float* __restrict__ B,
                                          __bf16* __restrict__ hi,
                                          __bf16* __restrict__ lo,
                                          int pblk, int NT, int KK, int ld, int col0) {
    const int gid = pblk * 256 + threadIdx.x;
    if (gid >= NT * KK * 64) return;
    const int lane = gid & 63;
    const int rem  = gid >> 6;
    const int kk   = rem % KK;
    const int t    = rem / KK;
    const int n    = col0 + t * 16 + (lane & 15);
    const int k0   = kk * 32 + (lane >> 4) * 8;
#pragma unroll
    for (int j = 0; j < 8; j++) {
        const float v = B[(size_t)(k0 + j) * ld + n];
        const __bf16 h = (__bf16)v;
        hi[(size_t)gid * 8 + j] = h;
        lo[(size_t)gid * 8 + j] = (__bf16)(v - (float)h);
    }
}

// ---------------------------------------------------------------------------
// prep: [deg histogram | pack W1 | pack W2 | x -> bf16 copy] by block range.
// ---------------------------------------------------------------------------
__global__ __launch_bounds__(256) void prep_kernel(const int* __restrict__ ei,
                                                   int* __restrict__ deg,
                                                   const float* __restrict__ W1,
                                                   __bf16* __restrict__ B1h,
                                                   __bf16* __restrict__ B1l,
                                                   const float* __restrict__ W2,
                                                   __bf16* __restrict__ B2h,
                                                   __bf16* __restrict__ B2l,
                                                   const float* __restrict__ x,
                                                   __bf16* __restrict__ xb) {
    const int b = blockIdx.x;
    if (b < DEG_BLOCKS) {
        const int e = b * 256 + threadIdx.x;
        if (e < N_EDGES) atomicAdd(&deg[ei[N_EDGES + e]], 1);
        return;
    }
    const int pb = b - DEG_BLOCKS;
    if (pb < 16) {
        const int head = pb >> 2;
        pack_frag(W1, B1h + head * W1_FRAG, B1l + head * W1_FRAG,
                  pb & 3, 4, 4, F1, head * HID);
        return;
    }
    if (pb < 32) {
        pack_frag(W2, B2h, B2l, pb - 16, 8, 8, EMB, 0);
        return;
    }
    // x -> bf16 (float4 in, 4x bf16 out)
    const int i = (pb - 32) * 256 + threadIdx.x;  // quad index
    const float4 v = *(const float4*)&x[(size_t)i * 4];
    __bf16 o[4] = {(__bf16)v.x, (__bf16)v.y, (__bf16)v.z, (__bf16)v.w};
    *(ulong1*)&xb[(size_t)i * 4] = *(ulong1*)o;
}

// ---------------------------------------------------------------------------
// 3-phase parallel scan (deg -> off). Phase C also zeroes cur, fills
// rowd[off[i]..off[i]+deg[i]) = i (coalesced runs), and seeds the per-bucket
// append cursors gcur[b] = off[b*256] for the pass-1 bucketed edge append.
// ---------------------------------------------------------------------------
__global__ __launch_bounds__(256) void scanA_kernel(const int* __restrict__ deg,
                                                    int* __restrict__ off,
                                                    int* __restrict__ partial, int N) {
    __shared__ int sm[256];
    const int t = threadIdx.x;
    const int i = blockIdx.x * 256 + t;
    const int v = (i < N) ? deg[i] : 0;
    sm[t] = v;
    __syncthreads();
    int val = v;
#pragma unroll
    for (int o = 1; o < 256; o <<= 1) {
        const int add = (t >= o) ? sm[t - o] : 0;
        __syncthreads();
        val += add;
        sm[t] = val;
        __syncthreads();
    }
    if (i < N) off[i] = val - v;
    if (t == 255) partial[blockIdx.x] = val;
}

__global__ __launch_bounds__(256) void scanB_kernel(int* __restrict__ partial,
                                                    int* __restrict__ off_last) {
    __shared__ int sm[256];
    const int t = threadIdx.x;
    const int v = (t < SCAN_BLOCKS) ? partial[t] : 0;
    sm[t] = v;
    __syncthreads();
    int val = v;
#pragma unroll
    for (int o = 1; o < 256; o <<= 1) {
        const int add = (t >= o) ? sm[t - o] : 0;
        __syncthreads();
        val += add;
        sm[t] = val;
        __syncthreads();
    }
    if (t < SCAN_BLOCKS) partial[t] = val - v;
    if (t == SCAN_BLOCKS - 1) *off_last = val;
}

__global__ __launch_bounds__(256) void scanC_kernel(int* __restrict__ off,
                                                    const int* __restrict__ partial,
                                                    const int* __restrict__ deg,
                                                    int* __restrict__ cur,
                                                    int* __restrict__ rowd,
                                                    int* __restrict__ gcur, int N) {
    const int i = blockIdx.x * 256 + threadIdx.x;
    if (i < N) {
        const int o = off[i] + partial[blockIdx.x];
        off[i] = o;
        cur[i] = 0;
        if ((i & 255) == 0) gcur[i >> 8] = o;   // bucket append cursor
        const int d = deg[i];
        for (int j = 0; j < d; j++) rowd[o + j] = i;
    }
}

// ---------------------------------------------------------------------------
// gemm1 body: as1/ad1 = alpha-logits of (x @ W1). No C store.
// ---------------------------------------------------------------------------
__device__ __forceinline__ void gemm1_body(int blk,
        const float* __restrict__ A, const __bf16* __restrict__ Bh,
        const __bf16* __restrict__ Bl, const float* __restrict__ avs,
        const float* __restrict__ avd, float* __restrict__ as_out,
        float* __restrict__ ad_out, int M) {
    constexpr int NT = F1 / 16, KK = IN_DIM / 32, NH = HEADS;
    constexpr int Ncols = NT * 16;
    constexpr int K = KK * 32;
    const int tid  = threadIdx.x;
    const int wave = tid >> 6, lane = tid & 63;
    const int quad = lane >> 4, l16 = lane & 15;
    const int rowA = min(blk * 64 + wave * 16 + l16, M - 1);

    f32x4 acc[NT];
#pragma unroll
    for (int t = 0; t < NT; t++) acc[t] = (f32x4){0.f, 0.f, 0.f, 0.f};

    for (int kk = 0; kk < KK; kk++) {
        const int k0 = kk * 32 + quad * 8;
        float a8[8];
        *(float4*)&a8[0] = *(const float4*)&A[(size_t)rowA * K + k0];
        *(float4*)&a8[4] = *(const float4*)&A[(size_t)rowA * K + k0 + 4];
        bf16x8 ah, al;
#pragma unroll
        for (int j = 0; j < 8; j++) {
            const __bf16 h = (__bf16)a8[j];
            ah[j] = h;
            al[j] = (__bf16)(a8[j] - (float)h);
        }
#pragma unroll
        for (int t = 0; t < NT; t++) {
            const size_t bi = ((size_t)(t * KK + kk) * 64 + lane) * 8;
            bf16x8 bhv = *(const bf16x8*)&Bh[bi];
            bf16x8 blv = *(const bf16x8*)&Bl[bi];
            acc[t] = __builtin_amdgcn_mfma_f32_16x16x32_bf16(ah, bhv, acc[t], 0, 0, 0);
            acc[t] = __builtin_amdgcn_mfma_f32_16x16x32_bf16(al, bhv, acc[t], 0, 0, 0);
            acc[t] = __builtin_amdgcn_mfma_f32_16x16x32_bf16(ah, blv, acc[t], 0, 0, 0);
        }
    }

    const int rowS = blk * 64 + wave * 16 + quad * 4;
#pragma unroll
    for (int r = 0; r < 4; r++) {
        float ps[NH], pd[NH];
#pragma unroll
        for (int h = 0; h < NH; h++) { ps[h] = 0.f; pd[h] = 0.f; }
#pragma unroll
        for (int t = 0; t < NT; t++) {
            const int h = (t * 16) / (Ncols / NH);
            const int col = t * 16 + l16;
            ps[h] += acc[t][r] * avs[col];
            pd[h] += acc[t][r] * avd[col];
        }
#pragma unroll
        for (int o = 1; o < 16; o <<= 1) {
#pragma unroll
            for (int h = 0; h < NH; h++) {
                ps[h] += __shfl_xor(ps[h], o);
                pd[h] += __shfl_xor(pd[h], o);
            }
        }
        const int rr = rowS + r;
        if (l16 == 0 && rr < M) {
#pragma unroll
            for (int h = 0; h < NH; h++) {
                as_out[rr * NH + h] = ps[h];
                ad_out[rr * NH + h] = pd[h];
            }
        }
    }
}

// gemm1 + pass-1 bucketed edge append in one dispatch (independent block
// ranges). Pass 1: per-block LDS histogram over 196 buckets -> one global
// atomicAdd per (block,bucket) -> dense contiguous stage runs of packed
// u32 (s | d<<16) records. Writes combine in L2 (runs of ~42 x 4 B vs the
// old fully-random 4 B scatter's 64 B/write amplification).
__global__ __launch_bounds__(256) void gemm1_scatter_kernel(
        const float* __restrict__ A, const __bf16* __restrict__ Bh,
        const __bf16* __restrict__ Bl, const float* __restrict__ avs,
        const float* __restrict__ avd, float* __restrict__ as_out,
        float* __restrict__ ad_out, int M,
        const int* __restrict__ ei, int* __restrict__ gcur,
        unsigned* __restrict__ stage) {
    if (blockIdx.x < GEMM1_BLOCKS) {
        gemm1_body(blockIdx.x, A, Bh, Bl, avs, avd, as_out, ad_out, M);
        return;
    }
    __shared__ int lhist[NBUCK];
    __shared__ int lbase[NBUCK];
    const int tid = threadIdx.x;
    const int e0  = (blockIdx.x - GEMM1_BLOCKS) * P1_CHUNK;
    for (int b = tid; b < NBUCK; b += 256) lhist[b] = 0;
    __syncthreads();
    for (int i = 0; i < P1_CHUNK / 256; i++) {
        const int e = e0 + i * 256 + tid;
        if (e < N_EDGES) atomicAdd(&lhist[ei[N_EDGES + e] >> 8], 1);
    }
    __syncthreads();
    for (int b = tid; b < NBUCK; b += 256) {
        const int c = lhist[b];
        lbase[b] = c ? atomicAdd(&gcur[b], c) : 0;
    }
    __syncthreads();
    for (int b = tid; b < NBUCK; b += 256) lhist[b] = 0;
    __syncthreads();
    for (int i = 0; i < P1_CHUNK / 256; i++) {
        const int e = e0 + i * 256 + tid;
        if (e < N_EDGES) {
            const int s = ei[e], d = ei[N_EDGES + e];
            const int bk = d >> 8;
            const int r  = atomicAdd(&lhist[bk], 1);
            stage[lbase[bk] + r] = (unsigned)s | ((unsigned)d << 16);
        }
    }
}

// Pass 2 (absorbs the former w1_kernel): read bucket-grouped stage linearly,
// distribute within the bucket's ~16 KB col / ~64 KB w4 windows (L2-hot
// lines, single-XCD mostly), and compute the layer-1 edge weights directly.
__global__ __launch_bounds__(256) void w1s_kernel(const unsigned* __restrict__ stage,
                                                  const int* __restrict__ off,
                                                  int* __restrict__ cur,
                                                  const float* __restrict__ as1,
                                                  const float* __restrict__ ad1,
                                                  int* __restrict__ col,
                                                  float4* __restrict__ w4, int E) {
    const int i = blockIdx.x * 256 + threadIdx.x;
    if (i >= E) return;
    const unsigned p = stage[i];
    const int s = (int)(p & 0xFFFFu);
    const int d = (int)(p >> 16);
    const float4 a = *(const float4*)&as1[s * HEADS];
    const float4 b = *(const float4*)&ad1[d * HEADS];
    const int pos = off[d] + atomicAdd(&cur[d], 1);
    float4 o;
    o.x = expf(lrelu(a.x + b.x));
    o.y = expf(lrelu(a.y + b.y));
    o.z = expf(lrelu(a.z + b.z));
    o.w = expf(lrelu(a.w + b.w));
    col[pos] = s;
    w4[pos] = o;
}

// Layer-2 edge weights (one exp per edge instead of 64).
__global__ __launch_bounds__(256) void w2_kernel(const int* __restrict__ col,
                                                 const int* __restrict__ row,
                                                 const float* __restrict__ as2,
                                                 const float* __restrict__ ad2,
                                                 float* __restrict__ w2, int E) {
    const int i = blockIdx.x * 256 + threadIdx.x;
    if (i >= E) return;
    w2[i] = expf(lrelu(as2[col[i]] + ad2[row[i]]));
}

// ---------------------------------------------------------------------------
// Layer-1 x-aggregation: bf16 x gather, f32 accumulate; output pre-split into
// bf16 hi/lo planes so gemm12 loads MFMA A-fragments with ZERO repack VALU.
// ---------------------------------------------------------------------------
__global__ __launch_bounds__(256) void agg1x_kernel(const int* __restrict__ off,
                                                    const int* __restrict__ col,
                                                    const float4* __restrict__ w4,
                                                    const __bf16* __restrict__ xb,
                                                    const float* __restrict__ as1,
                                                    const float* __restrict__ ad1,
                                                    __bf16* __restrict__ aggxh,
                                                    __bf16* __restrict__ aggxl, int N) {
    const int w = __builtin_amdgcn_readfirstlane((blockIdx.x * 256 + threadIdx.x) >> 6);
    const int lane = threadIdx.x & 63;
    if (w >= N) return;

    float2 acc[HEADS];
    float z[HEADS];
#pragma unroll
    for (int h = 0; h < HEADS; h++) { acc[h] = make_float2(0.f, 0.f); z[h] = 0.f; }

    {   // self-loop
        const float4 asv = *(const float4*)&as1[w * HEADS];
        const float4 adv = *(const float4*)&ad1[w * HEADS];
        const bf16x2 xv = *(const bf16x2*)&xb[(size_t)w * IN_DIM + lane * 2];
        const float vx = (float)xv[0], vy = (float)xv[1];
        float ws[HEADS] = {expf(lrelu(asv.x + adv.x)), expf(lrelu(asv.y + adv.y)),
                           expf(lrelu(asv.z + adv.z)), expf(lrelu(asv.w + adv.w))};
#pragma unroll
        for (int h = 0; h < HEADS; h++) {
            acc[h].x += ws[h] * vx; acc[h].y += ws[h] * vy; z[h] += ws[h];
        }
    }
    const int jb = off[w], je = off[w + 1];
    int j = jb;
    for (; j + 3 < je; j += 4) {
        const int s0 = col[j], s1 = col[j + 1], s2 = col[j + 2], s3 = col[j + 3];
        const float4 w0 = w4[j], w1 = w4[j + 1], w2 = w4[j + 2], w3 = w4[j + 3];
        const bf16x2 b0 = *(const bf16x2*)&xb[(size_t)s0 * IN_DIM + lane * 2];
        const bf16x2 b1 = *(const bf16x2*)&xb[(size_t)s1 * IN_DIM + lane * 2];
        const bf16x2 b2 = *(const bf16x2*)&xb[(size_t)s2 * IN_DIM + lane * 2];
        const bf16x2 b3 = *(const bf16x2*)&xb[(size_t)s3 * IN_DIM + lane * 2];
        const float v0x = (float)b0[0], v0y = (float)b0[1];
        const float v1x = (float)b1[0], v1y = (float)b1[1];
        const float v2x = (float)b2[0], v2y = (float)b2[1];
        const float v3x = (float)b3[0], v3y = (float)b3[1];
        acc[0].x += w0.x * v0x + w1.x * v1x + w2.x * v2x + w3.x * v3x;
        acc[0].y += w0.x * v0y + w1.x * v1y + w2.x * v2y + w3.x * v3y;
        acc[1].x += w0.y * v0x + w1.y * v1x + w2.y * v2x + w3.y * v3x;
        acc[1].y += w0.y * v0y + w1.y * v1y + w2.y * v2y + w3.y * v3y;
        acc[2].x += w0.z * v0x + w1.z * v1x + w2.z * v2x + w3.z * v3x;
        acc[2].y += w0.z * v0y + w1.z * v1y + w2.z * v2y + w3.z * v3y;
        acc[3].x += w0.w * v0x + w1.w * v1x + w2.w * v2x + w3.w * v3x;
        acc[3].y += w0.w * v0y + w1.w * v1y + w2.w * v2y + w3.w * v3y;
        z[0] += (w0.x + w1.x) + (w2.x + w3.x);
        z[1] += (w0.y + w1.y) + (w2.y + w3.y);
        z[2] += (w0.z + w1.z) + (w2.z + w3.z);
        z[3] += (w0.w + w1.w) + (w2.w + w3.w);
    }
    for (; j < je; j++) {
        const int s0 = col[j];
        const float4 w0 = w4[j];
        const bf16x2 b0 = *(const bf16x2*)&xb[(size_t)s0 * IN_DIM + lane * 2];
        const float v0x = (float)b0[0], v0y = (float)b0[1];
        acc[0].x += w0.x * v0x; acc[0].y += w0.x * v0y; z[0] += w0.x;
        acc[1].x += w0.y * v0x; acc[1].y += w0.y * v0y; z[1] += w0.y;
        acc[2].x += w0.z * v0x; acc[2].y += w0.z * v0y; z[2] += w0.z;
        acc[3].x += w0.w * v0x; acc[3].y += w0.w * v0y; z[3] += w0.w;
    }
#pragma unroll
    for (int h = 0; h < HEADS; h++) {
        const float inv = 1.f / z[h];
        const float vx = acc[h].x * inv, vy = acc[h].y * inv;
        const __bf16 hx = (__bf16)vx, hy = (__bf16)vy;
        bf16x2 hv = {hx, hy};
        bf16x2 lv = {(__bf16)(vx - (float)hx), (__bf16)(vy - (float)hy)};
        const size_t o = ((size_t)w * HEADS + h) * IN_DIM + lane * 2;
        *(bf16x2*)&aggxh[o] = hv;
        *(bf16x2*)&aggxl[o] = lv;
    }
}

// ---------------------------------------------------------------------------
// FUSED layer-1-reconstruct + layer-2 GEMM, 16 rows/block, 4 waves.
// A-operands (aggx) and the inter-layer LDS tile are pre-split bf16 hi/lo.
// ---------------------------------------------------------------------------
__global__ __launch_bounds__(256) void gemm12_kernel(
        const __bf16* __restrict__ aggxh, const __bf16* __restrict__ aggxl,
        const __bf16* __restrict__ B1h, const __bf16* __restrict__ B1l,
        const float* __restrict__ b1,
        const __bf16* __restrict__ B2h, const __bf16* __restrict__ B2l,
        const float* __restrict__ avs, const float* __restrict__ avd,
        __bf16* __restrict__ g2b, float* __restrict__ as_out,
        float* __restrict__ ad_out, int M) {
    __shared__ __bf16 smh[16 * LDSB];
    __shared__ __bf16 sml[16 * LDSB];
    __shared__ float pps[4][16], pdd[4][16];
    const int tid  = threadIdx.x;
    const int wave = tid >> 6, lane = tid & 63;
    const int quad = lane >> 4, l16 = lane & 15;
    const int row0 = blockIdx.x * 16;
    const int rowA = min(row0 + l16, M - 1);

    // ---- phase 1: this wave's head = `wave`; A-fragments direct from planes
    {
        f32x4 acc1[4];
#pragma unroll
        for (int t = 0; t < 4; t++) acc1[t] = (f32x4){0.f, 0.f, 0.f, 0.f};
        const size_t abase = ((size_t)rowA * HEADS + wave) * IN_DIM;
#pragma unroll
        for (int kk = 0; kk < 4; kk++) {
            const int k0 = kk * 32 + quad * 8;
            bf16x8 ah = *(const bf16x8*)&aggxh[abase + k0];
            bf16x8 al = *(const bf16x8*)&aggxl[abase + k0];
#pragma unroll
            for (int t = 0; t < 4; t++) {
                const size_t bi = (size_t)wave * W1_FRAG +
                                  ((size_t)(t * 4 + kk) * 64 + lane) * 8;
                bf16x8 bhv = *(const bf16x8*)&B1h[bi];
                bf16x8 blv = *(const bf16x8*)&B1l[bi];
                acc1[t] = __builtin_amdgcn_mfma_f32_16x16x32_bf16(ah, bhv, acc1[t], 0, 0, 0);
                acc1[t] = __builtin_amdgcn_mfma_f32_16x16x32_bf16(al, bhv, acc1[t], 0, 0, 0);
                acc1[t] = __builtin_amdgcn_mfma_f32_16x16x32_bf16(ah, blv, acc1[t], 0, 0, 0);
            }
        }
        // ELU(+b1) -> LDS hi/lo planes (split once here, consumed raw below)
#pragma unroll
        for (int t = 0; t < 4; t++) {
            const int c = wave * 64 + t * 16 + l16;
            const float bb = b1[c];
#pragma unroll
            for (int r = 0; r < 4; r++) {
                const float v = eluf(acc1[t][r] + bb);
                const __bf16 hh = (__bf16)v;
                smh[(quad * 4 + r) * LDSB + c] = hh;
                sml[(quad * 4 + r) * LDSB + c] = (__bf16)(v - (float)hh);
            }
        }
    }
    __syncthreads();

    // ---- phase 2: this wave's output cols = tiles {2*wave, 2*wave+1} ----
    f32x4 acc2[2];
#pragma unroll
    for (int t = 0; t < 2; t++) acc2[t] = (f32x4){0.f, 0.f, 0.f, 0.f};
    const int arow = l16 * LDSB;
#pragma unroll
    for (int kk = 0; kk < 8; kk++) {
        const int k0 = kk * 32 + quad * 8;
        bf16x8 ah = *(const bf16x8*)&smh[arow + k0];
        bf16x8 al = *(const bf16x8*)&sml[arow + k0];
#pragma unroll
        for (int tt = 0; tt < 2; tt++) {
            const int t = wave * 2 + tt;
            const size_t bi = ((size_t)(t * 8 + kk) * 64 + lane) * 8;
            bf16x8 bhv = *(const bf16x8*)&B2h[bi];
            bf16x8 blv = *(const bf16x8*)&B2l[bi];
            acc2[tt] = __builtin_amdgcn_mfma_f32_16x16x32_bf16(ah, bhv, acc2[tt], 0, 0, 0);
            acc2[tt] = __builtin_amdgcn_mfma_f32_16x16x32_bf16(al, bhv, acc2[tt], 0, 0, 0);
            acc2[tt] = __builtin_amdgcn_mfma_f32_16x16x32_bf16(ah, blv, acc2[tt], 0, 0, 0);
        }
    }

    // store g2 (bf16) + alpha2 logit partials (f32, exact from acc2)
    const int rowS = row0 + quad * 4;
#pragma unroll
    for (int tt = 0; tt < 2; tt++) {
        const int t = wave * 2 + tt;
#pragma unroll
        for (int r = 0; r < 4; r++) {
            const int rr = rowS + r;
            if (rr < M) g2b[(size_t)rr * EMB + t * 16 + l16] = (__bf16)acc2[tt][r];
        }
    }
#pragma unroll
    for (int r = 0; r < 4; r++) {
        float ps = 0.f, pd = 0.f;
#pragma unroll
        for (int tt = 0; tt < 2; tt++) {
            const int c = (wave * 2 + tt) * 16 + l16;
            ps += acc2[tt][r] * avs[c];
            pd += acc2[tt][r] * avd[c];
        }
#pragma unroll
        for (int o = 1; o < 16; o <<= 1) {
            ps += __shfl_xor(ps, o);
            pd += __shfl_xor(pd, o);
        }
        if (l16 == 0) {
            pps[wave][quad * 4 + r] = ps;
            pdd[wave][quad * 4 + r] = pd;
        }
    }
    __syncthreads();
    if (tid < 16) {
        const int rr = row0 + tid;
        if (rr < M) {
            as_out[rr] = pps[0][tid] + pps[1][tid] + pps[2][tid] + pps[3][tid];
            ad_out[rr] = pdd[0][tid] + pdd[1][tid] + pdd[2][tid] + pdd[3][tid];
        }
    }
}

// ---------------------------------------------------------------------------
// Layer-2 aggregation: one wave per dst node, bf16 g2 gather, f32 weights.
// ---------------------------------------------------------------------------
__global__ __launch_bounds__(256) void agg2_kernel(const int* __restrict__ off,
                                                   const int* __restrict__ col,
                                                   const float* __restrict__ w2,
                                                   const __bf16* __restrict__ g2b,
                                                   const float* __restrict__ as2,
                                                   const float* __restrict__ ad2,
                                                   float* __restrict__ out2, int N) {
    const int w = __builtin_amdgcn_readfirstlane((blockIdx.x * 256 + threadIdx.x) >> 6);
    const int lane = threadIdx.x & 63;
    if (w >= N) return;

    float2 acc = make_float2(0.f, 0.f);
    float z = 0.f;
    {   // self-loop
        const float wt = expf(lrelu(as2[w] + ad2[w]));
        const bf16x2 hv = *(const bf16x2*)&g2b[(size_t)w * EMB + lane * 2];
        acc.x += wt * (float)hv[0]; acc.y += wt * (float)hv[1];
        z += wt;
    }
    const int jb = off[w], je = off[w + 1];
    int j = jb;
    for (; j + 3 < je; j += 4) {
        const int s0 = col[j], s1 = col[j + 1], s2 = col[j + 2], s3 = col[j + 3];
        const float w0 = w2[j], w1 = w2[j + 1], w2v = w2[j + 2], w3 = w2[j + 3];
        const bf16x2 b0 = *(const bf16x2*)&g2b[(size_t)s0 * EMB + lane * 2];
        const bf16x2 b1 = *(const bf16x2*)&g2b[(size_t)s1 * EMB + lane * 2];
        const bf16x2 b2 = *(const bf16x2*)&g2b[(size_t)s2 * EMB + lane * 2];
        const bf16x2 b3 = *(const bf16x2*)&g2b[(size_t)s3 * EMB + lane * 2];
        acc.x += w0 * (float)b0[0] + w1 * (float)b1[0] + w2v * (float)b2[0] + w3 * (float)b3[0];
        acc.y += w0 * (float)b0[1] + w1 * (float)b1[1] + w2v * (float)b2[1] + w3 * (float)b3[1];
        z += (w0 + w1) + (w2v + w3);
    }
    for (; j < je; j++) {
        const int s0 = col[j];
        const float w0 = w2[j];
        const bf16x2 b0 = *(const bf16x2*)&g2b[(size_t)s0 * EMB + lane * 2];
        acc.x += w0 * (float)b0[0]; acc.y += w0 * (float)b0[1];
        z += w0;
    }
    const float inv = 1.f / z;
    float2 o = make_float2(acc.x * inv, acc.y * inv);
    *(float2*)&out2[(size_t)w * EMB + lane * 2] = o;
}

// ---------------------------------------------------------------------------
// Global mean pool (782-block run-length form) + divide.
// ---------------------------------------------------------------------------
__global__ __launch_bounds__(128) void pool_kernel(const float* __restrict__ out2,
                                                   const float* __restrict__ b2,
                                                   const int* __restrict__ batch,
                                                   float* __restrict__ pool,
                                                   float* __restrict__ cnt, int N) {
    const int c = threadIdx.x;
    const int n0 = blockIdx.x * 64;
    const int nend = min(n0 + 64, N);
    const float bias = b2[c];
    float acc = 0.f, cacc = 0.f;
    int curg = batch[n0];
    for (int n = n0; n < nend; n++) {
        const int g = batch[n];
        if (g != curg) {
            atomicAdd(&pool[curg * EMB + c], acc);
            if (c == 0) atomicAdd(&cnt[curg], cacc);
            acc = 0.f; cacc = 0.f; curg = g;
        }
        float v = out2[(size_t)n * EMB + c] + bias;
        v = v > 0.f ? v : expm1f(v);
        acc += v;
        cacc += 1.f;
    }
    atomicAdd(&pool[curg * EMB + c], acc);
    if (c == 0) atomicAdd(&cnt[curg], cacc);
}

__global__ __launch_bounds__(256) void div_kernel(const float* __restrict__ pool,
                                                  const float* __restrict__ cnt,
                                                  float* __restrict__ out) {
    const int i = blockIdx.x * 256 + threadIdx.x;
    out[i] = pool[i] / fmaxf(cnt[i >> 7], 1.f);
}

// ---------------------------------------------------------------------------
extern "C" void kernel_launch(void* const* d_in, const int* in_sizes, int n_in,
                              void* d_out, int out_size, void* d_ws, size_t ws_size,
                              hipStream_t stream) {
    const float* x      = (const float*)d_in[0];
    const int*   ei     = (const int*)d_in[1];
    const int*   batch  = (const int*)d_in[3];
    const float* W1     = (const float*)d_in[4];
    const float* a_src1 = (const float*)d_in[5];
    const float* a_dst1 = (const float*)d_in[6];
    const float* b1     = (const float*)d_in[7];
    const float* W2     = (const float*)d_in[8];
    const float* a_src2 = (const float*)d_in[9];
    const float* a_dst2 = (const float*)d_in[10];
    const float* b2     = (const float*)d_in[11];
    float* out = (float*)d_out;

    const int N = N_NODES, E = N_EDGES;

    size_t cur_off = 0;
    auto carve = [&](size_t bytes) {
        size_t o = cur_off;
        cur_off = (cur_off + bytes + 255) & ~(size_t)255;
        return (char*)d_ws + o;
    };
    // zero-init region: deg + pool + cnt
    int* deg     = (int*)carve((size_t)N * 4);
    float* pool  = (float*)carve((size_t)N_GRAPHS * EMB * 4);
    float* cnt   = (float*)carve((size_t)N_GRAPHS * 4);
    const size_t zero_bytes = cur_off;
    int* curp    = (int*)carve((size_t)N * 4);
    int* partial = (int*)carve((size_t)SCAN_BLOCKS * 4);
    int* gcur    = (int*)carve((size_t)NBUCK * 4);
    unsigned* stage = (unsigned*)carve((size_t)E * 4);
    __bf16* B1h  = (__bf16*)carve((size_t)HEADS * W1_FRAG * 2);
    __bf16* B1l  = (__bf16*)carve((size_t)HEADS * W1_FRAG * 2);
    __bf16* B2h  = (__bf16*)carve((size_t)F1 * EMB * 2);
    __bf16* B2l  = (__bf16*)carve((size_t)F1 * EMB * 2);
    __bf16* xb   = (__bf16*)carve((size_t)N * IN_DIM * 2);
    int* off     = (int*)carve((size_t)(N + 1) * 4);
    int* col     = (int*)carve((size_t)E * 4);
    int* rowd    = (int*)carve((size_t)E * 4);
    float4* w4   = (float4*)carve((size_t)E * 16);
    float* w2    = (float*)carve((size_t)E * 4);
    __bf16* aggxh = (__bf16*)carve((size_t)N * HEADS * IN_DIM * 2);
    __bf16* aggxl = (__bf16*)carve((size_t)N * HEADS * IN_DIM * 2);
    __bf16* g2b  = (__bf16*)carve((size_t)N * EMB * 2);
    float* out2  = (float*)carve((size_t)N * EMB * 4);
    float* as1   = (float*)carve((size_t)N * HEADS * 4);
    float* ad1   = (float*)carve((size_t)N * HEADS * 4);
    float* as2   = (float*)carve((size_t)N * 4);
    float* ad2   = (float*)carve((size_t)N * 4);

    hipMemsetAsync(d_ws, 0, zero_bytes, stream);

    prep_kernel<<<DEG_BLOCKS + 32 + XCONV_BLOCKS, 256, 0, stream>>>(
        ei, deg, W1, B1h, B1l, W2, B2h, B2l, x, xb);

    scanA_kernel<<<SCAN_BLOCKS, 256, 0, stream>>>(deg, off, partial, N);
    scanB_kernel<<<1, 256, 0, stream>>>(partial, &off[N]);
    scanC_kernel<<<SCAN_BLOCKS, 256, 0, stream>>>(off, partial, deg, curp, rowd, gcur, N);

    // gemm1 (x -> as1/ad1) + bucketed edge append (pass 1), one dispatch
    gemm1_scatter_kernel<<<GEMM1_BLOCKS + P1_BLOCKS, 256, 0, stream>>>(
        x, B1h, B1l, a_src1, a_dst1, as1, ad1, N, ei, gcur, stage);

    // pass 2: bucket-local distribution + layer-1 edge weights (fused old w1)
    w1s_kernel<<<DEG_BLOCKS, 256, 0, stream>>>(stage, off, curp, as1, ad1, col, w4, E);

    agg1x_kernel<<<(N + 3) / 4, 256, 0, stream>>>(off, col, w4, xb, as1, ad1,
                                                  aggxh, aggxl, N);

    // fused: (aggx @ W1 -> ELU -> @ W2) + alpha2; all operands pre-split bf16
    gemm12_kernel<<<(N + 15) / 16, 256, 0, stream>>>(aggxh, aggxl, B1h, B1l, b1,
                                                     B2h, B2l, a_src2, a_dst2,
                                                     g2b, as2, ad2, N);

    w2_kernel<<<DEG_BLOCKS, 256, 0, stream>>>(col, rowd, as2, ad2, w2, E);
    agg2_kernel<<<(N + 3) / 4, 256, 0, stream>>>(off, col, w2, g2b, as2, ad2, out2, N);

    pool_kernel<<<(N + 63) / 64, 128, 0, stream>>>(out2, b2, batch, pool, cnt, N);
    div_kernel<<<(N_GRAPHS * EMB) / 256, 256, 0, stream>>>(pool, cnt, out);
}

// Round 2
// 356.265 us; speedup vs baseline: 1.0252x; 1.0252x over previous
//
#include <hip/hip_runtime.h>
#include <hip/hip_bf16.h>
#include <cstddef>

// Problem constants (fixed-shape problem)
constexpr int N_NODES = 50000;
constexpr int N_EDGES = 800000;
constexpr int IN_DIM  = 128;
constexpr int HID     = 64;
constexpr int HEADS   = 4;
constexpr int F1      = HEADS * HID;  // 256
constexpr int EMB     = 128;
constexpr int N_GRAPHS = 64;

constexpr int DEG_BLOCKS   = (N_EDGES + 255) / 256;          // 3125
constexpr int SCAN_BLOCKS  = (N_NODES + 255) / 256;          // 196
constexpr int GEMM1_BLOCKS = (N_NODES + 63) / 64;            // 782
constexpr int XCONV_BLOCKS = (N_NODES * IN_DIM / 4) / 256;   // 6250 (exact)
// per-head W1 fragment size (NT=4, KK=4): 4*4*64*8 bf16 elements
constexpr int W1_FRAG = 4 * 4 * 64 * 8;                      // 8192
// gemm12 LDS tile stride in bf16 elems: 264*2 = 528 B rows (16 B aligned for
// ds_read_b128; 132 dwords mod 32 = 4 -> ~2-way bank alias, free per m136)
constexpr int LDSB = 264;
// fused-aggregate LDS node-row stride: 4*128+8 elems = 1040 B (16 B aligned,
// 260 dwords mod 32 = 4 -> same mild alias class as LDSB)
constexpr int AXS  = HEADS * IN_DIM + 8;                     // 520
// bucketed CSR build (round-1): 256-node buckets, pass-1 appends packed
// (s|d<<16) records per bucket, pass-2 distributes within bucket windows.
constexpr int NBUCK    = (N_NODES + 255) / 256;              // 196
constexpr int P1_CHUNK = 8192;                               // edges per pass-1 block
constexpr int P1_BLOCKS = (N_EDGES + P1_CHUNK - 1) / P1_CHUNK; // 98
constexpr int AGG12_BLOCKS = N_NODES / 16;                   // 3125 (exact)
static_assert(N_NODES % 16 == 0, "fused agg+gemm12 assumes exact 16-row tiles");

typedef __bf16 bf16x8 __attribute__((ext_vector_type(8)));
typedef __bf16 bf16x2 __attribute__((ext_vector_type(2)));
typedef float  f32x4  __attribute__((ext_vector_type(4)));

__device__ __forceinline__ float lrelu(float x) { return x > 0.f ? x : 0.2f * x; }
__device__ __forceinline__ float eluf(float x)  { return x > 0.f ? x : expm1f(x); }

// ---------------------------------------------------------------------------
// Pack a [K x 16*NT] submatrix of B (leading dim ld, origin col0) into
// per-lane MFMA B-fragments, split hi/lo bf16.
// ---------------------------------------------------------------------------
__device__ __forceinline__ void pack_frag(const float* __restrict__ B,
                                          __bf16* __restrict__ hi,
                                          __bf16* __restrict__ lo,
                                          int pblk, int NT, int KK, int ld, int col0) {
    const int gid = pblk * 256 + threadIdx.x;
    if (gid >= NT * KK * 64) return;
    const int lane = gid & 63;
    const int rem  = gid >> 6;
    const int kk   = rem % KK;
    const int t    = rem / KK;
    const int n    = col0 + t * 16 + (lane & 15);
    const int k0   = kk * 32 + (lane >> 4) * 8;
#pragma unroll
    for (int j = 0; j < 8; j++) {
        const float v = B[(size_t)(k0 + j) * ld + n];
        const __bf16 h = (__bf16)v;
        hi[(size_t)gid * 8 + j] = h;
        lo[(size_t)gid * 8 + j] = (__bf16)(v - (float)h);
    }
}

// ---------------------------------------------------------------------------
// prep: [deg histogram | pack W1 | pack W2 | x -> bf16 copy] by block range.
// ---------------------------------------------------------------------------
__global__ __launch_bounds__(256) void prep_kernel(const int* __restrict__ ei,
                                                   int* __restrict__ deg,
                                                   const float* __restrict__ W1,
                                                   __bf16* __restrict__ B1h,
                                                   __bf16* __restrict__ B1l,
                                                   const float* __restrict__ W2,
                                                   __bf16* __restrict__ B2h,
                                                   __bf16* __restrict__ B2l,
                                                   const float* __restrict__ x,
                                                   __bf16* __restrict__ xb) {
    const int b = blockIdx.x;
    if (b < DEG_BLOCKS) {
        const int e = b * 256 + threadIdx.x;
        if (e < N_EDGES) atomicAdd(&deg[ei[N_EDGES + e]], 1);
        return;
    }
    const int pb = b - DEG_BLOCKS;
    if (pb < 16) {
        const int head = pb >> 2;
        pack_frag(W1, B1h + head * W1_FRAG, B1l + head * W1_FRAG,
                  pb & 3, 4, 4, F1, head * HID);
        return;
    }
    if (pb < 32) {
        pack_frag(W2, B2h, B2l, pb - 16, 8, 8, EMB, 0);
        return;
    }
    // x -> bf16 (float4 in, 4x bf16 out)
    const int i = (pb - 32) * 256 + threadIdx.x;  // quad index
    const float4 v = *(const float4*)&x[(size_t)i * 4];
    __bf16 o[4] = {(__bf16)v.x, (__bf16)v.y, (__bf16)v.z, (__bf16)v.w};
    *(ulong1*)&xb[(size_t)i * 4] = *(ulong1*)o;
}

// ---------------------------------------------------------------------------
// 3-phase parallel scan (deg -> off). Phase C also zeroes cur and seeds the
// per-bucket append cursors gcur[b] = off[b*256]. (rowd is gone: its only
// consumer, w2_kernel, got folded into agg2.)
// ---------------------------------------------------------------------------
__global__ __launch_bounds__(256) void scanA_kernel(const int* __restrict__ deg,
                                                    int* __restrict__ off,
                                                    int* __restrict__ partial, int N) {
    __shared__ int sm[256];
    const int t = threadIdx.x;
    const int i = blockIdx.x * 256 + t;
    const int v = (i < N) ? deg[i] : 0;
    sm[t] = v;
    __syncthreads();
    int val = v;
#pragma unroll
    for (int o = 1; o < 256; o <<= 1) {
        const int add = (t >= o) ? sm[t - o] : 0;
        __syncthreads();
        val += add;
        sm[t] = val;
        __syncthreads();
    }
    if (i < N) off[i] = val - v;
    if (t == 255) partial[blockIdx.x] = val;
}

__global__ __launch_bounds__(256) void scanB_kernel(int* __restrict__ partial,
                                                    int* __restrict__ off_last) {
    __shared__ int sm[256];
    const int t = threadIdx.x;
    const int v = (t < SCAN_BLOCKS) ? partial[t] : 0;
    sm[t] = v;
    __syncthreads();
    int val = v;
#pragma unroll
    for (int o = 1; o < 256; o <<= 1) {
        const int add = (t >= o) ? sm[t - o] : 0;
        __syncthreads();
        val += add;
        sm[t] = val;
        __syncthreads();
    }
    if (t < SCAN_BLOCKS) partial[t] = val - v;
    if (t == SCAN_BLOCKS - 1) *off_last = val;
}

__global__ __launch_bounds__(256) void scanC_kernel(int* __restrict__ off,
                                                    const int* __restrict__ partial,
                                                    int* __restrict__ cur,
                                                    int* __restrict__ gcur, int N) {
    const int i = blockIdx.x * 256 + threadIdx.x;
    if (i < N) {
        const int o = off[i] + partial[blockIdx.x];
        off[i] = o;
        cur[i] = 0;
        if ((i & 255) == 0) gcur[i >> 8] = o;   // bucket append cursor
    }
}

// ---------------------------------------------------------------------------
// gemm1 body: as1/ad1 = alpha-logits of (x @ W1). No C store.
// ---------------------------------------------------------------------------
__device__ __forceinline__ void gemm1_body(int blk,
        const float* __restrict__ A, const __bf16* __restrict__ Bh,
        const __bf16* __restrict__ Bl, const float* __restrict__ avs,
        const float* __restrict__ avd, float* __restrict__ as_out,
        float* __restrict__ ad_out, int M) {
    constexpr int NT = F1 / 16, KK = IN_DIM / 32, NH = HEADS;
    constexpr int Ncols = NT * 16;
    constexpr int K = KK * 32;
    const int tid  = threadIdx.x;
    const int wave = tid >> 6, lane = tid & 63;
    const int quad = lane >> 4, l16 = lane & 15;
    const int rowA = min(blk * 64 + wave * 16 + l16, M - 1);

    f32x4 acc[NT];
#pragma unroll
    for (int t = 0; t < NT; t++) acc[t] = (f32x4){0.f, 0.f, 0.f, 0.f};

    for (int kk = 0; kk < KK; kk++) {
        const int k0 = kk * 32 + quad * 8;
        float a8[8];
        *(float4*)&a8[0] = *(const float4*)&A[(size_t)rowA * K + k0];
        *(float4*)&a8[4] = *(const float4*)&A[(size_t)rowA * K + k0 + 4];
        bf16x8 ah, al;
#pragma unroll
        for (int j = 0; j < 8; j++) {
            const __bf16 h = (__bf16)a8[j];
            ah[j] = h;
            al[j] = (__bf16)(a8[j] - (float)h);
        }
#pragma unroll
        for (int t = 0; t < NT; t++) {
            const size_t bi = ((size_t)(t * KK + kk) * 64 + lane) * 8;
            bf16x8 bhv = *(const bf16x8*)&Bh[bi];
            bf16x8 blv = *(const bf16x8*)&Bl[bi];
            acc[t] = __builtin_amdgcn_mfma_f32_16x16x32_bf16(ah, bhv, acc[t], 0, 0, 0);
            acc[t] = __builtin_amdgcn_mfma_f32_16x16x32_bf16(al, bhv, acc[t], 0, 0, 0);
            acc[t] = __builtin_amdgcn_mfma_f32_16x16x32_bf16(ah, blv, acc[t], 0, 0, 0);
        }
    }

    const int rowS = blk * 64 + wave * 16 + quad * 4;
#pragma unroll
    for (int r = 0; r < 4; r++) {
        float ps[NH], pd[NH];
#pragma unroll
        for (int h = 0; h < NH; h++) { ps[h] = 0.f; pd[h] = 0.f; }
#pragma unroll
        for (int t = 0; t < NT; t++) {
            const int h = (t * 16) / (Ncols / NH);
            const int col = t * 16 + l16;
            ps[h] += acc[t][r] * avs[col];
            pd[h] += acc[t][r] * avd[col];
        }
#pragma unroll
        for (int o = 1; o < 16; o <<= 1) {
#pragma unroll
            for (int h = 0; h < NH; h++) {
                ps[h] += __shfl_xor(ps[h], o);
                pd[h] += __shfl_xor(pd[h], o);
            }
        }
        const int rr = rowS + r;
        if (l16 == 0 && rr < M) {
#pragma unroll
            for (int h = 0; h < NH; h++) {
                as_out[rr * NH + h] = ps[h];
                ad_out[rr * NH + h] = pd[h];
            }
        }
    }
}

// gemm1 + pass-1 bucketed edge append in one dispatch (independent block
// ranges). Pass 1: per-block LDS histogram over 196 buckets -> one global
// atomicAdd per (block,bucket) -> dense contiguous stage runs of packed
// u32 (s | d<<16) records.
__global__ __launch_bounds__(256) void gemm1_scatter_kernel(
        const float* __restrict__ A, const __bf16* __restrict__ Bh,
        const __bf16* __restrict__ Bl, const float* __restrict__ avs,
        const float* __restrict__ avd, float* __restrict__ as_out,
        float* __restrict__ ad_out, int M,
        const int* __restrict__ ei, int* __restrict__ gcur,
        unsigned* __restrict__ stage) {
    if (blockIdx.x < GEMM1_BLOCKS) {
        gemm1_body(blockIdx.x, A, Bh, Bl, avs, avd, as_out, ad_out, M);
        return;
    }
    __shared__ int lhist[NBUCK];
    __shared__ int lbase[NBUCK];
    const int tid = threadIdx.x;
    const int e0  = (blockIdx.x - GEMM1_BLOCKS) * P1_CHUNK;
    for (int b = tid; b < NBUCK; b += 256) lhist[b] = 0;
    __syncthreads();
    for (int i = 0; i < P1_CHUNK / 256; i++) {
        const int e = e0 + i * 256 + tid;
        if (e < N_EDGES) atomicAdd(&lhist[ei[N_EDGES + e] >> 8], 1);
    }
    __syncthreads();
    for (int b = tid; b < NBUCK; b += 256) {
        const int c = lhist[b];
        lbase[b] = c ? atomicAdd(&gcur[b], c) : 0;
    }
    __syncthreads();
    for (int b = tid; b < NBUCK; b += 256) lhist[b] = 0;
    __syncthreads();
    for (int i = 0; i < P1_CHUNK / 256; i++) {
        const int e = e0 + i * 256 + tid;
        if (e < N_EDGES) {
            const int s = ei[e], d = ei[N_EDGES + e];
            const int bk = d >> 8;
            const int r  = atomicAdd(&lhist[bk], 1);
            stage[lbase[bk] + r] = (unsigned)s | ((unsigned)d << 16);
        }
    }
}

// Pass 2: read bucket-grouped stage linearly, distribute within the bucket's
// small col/w4 windows (L2-hot), and compute the layer-1 edge weights.
__global__ __launch_bounds__(256) void w1s_kernel(const unsigned* __restrict__ stage,
                                                  const int* __restrict__ off,
                                                  int* __restrict__ cur,
                                                  const float* __restrict__ as1,
                                                  const float* __restrict__ ad1,
                                                  int* __restrict__ col,
                                                  float4* __restrict__ w4, int E) {
    const int i = blockIdx.x * 256 + threadIdx.x;
    if (i >= E) return;
    const unsigned p = stage[i];
    const int s = (int)(p & 0xFFFFu);
    const int d = (int)(p >> 16);
    const float4 a = *(const float4*)&as1[s * HEADS];
    const float4 b = *(const float4*)&ad1[d * HEADS];
    const int pos = off[d] + atomicAdd(&cur[d], 1);
    float4 o;
    o.x = expf(lrelu(a.x + b.x));
    o.y = expf(lrelu(a.y + b.y));
    o.z = expf(lrelu(a.z + b.z));
    o.w = expf(lrelu(a.w + b.w));
    col[pos] = s;
    w4[pos] = o;
}

// ---------------------------------------------------------------------------
// FUSED layer-1 aggregation + layer-1 GEMM + layer-2 GEMM, 16 rows/block.
// Phase 0 gather-aggregates the block's 16 nodes (one node per 16-lane
// group: 16 concurrent gather chains/block, bf16x8 16 B gathers) into padded
// LDS hi/lo planes, eliminating the 102 MB aggx HBM round-trip + a dispatch.
// ---------------------------------------------------------------------------
__global__ __launch_bounds__(256) void agg_gemm12_kernel(
        const int* __restrict__ off, const int* __restrict__ col,
        const float4* __restrict__ w4, const __bf16* __restrict__ xb,
        const float* __restrict__ as1, const float* __restrict__ ad1,
        const __bf16* __restrict__ B1h, const __bf16* __restrict__ B1l,
        const float* __restrict__ b1,
        const __bf16* __restrict__ B2h, const __bf16* __restrict__ B2l,
        const float* __restrict__ avs, const float* __restrict__ avd,
        __bf16* __restrict__ g2b, float* __restrict__ as_out,
        float* __restrict__ ad_out, int M) {
    __shared__ __bf16 axh[16 * AXS];          // 16.25 KB
    __shared__ __bf16 axl[16 * AXS];          // 16.25 KB
    __shared__ __bf16 smh[16 * LDSB];         // 8.25 KB
    __shared__ __bf16 sml[16 * LDSB];         // 8.25 KB
    __shared__ float pps[4][16], pdd[4][16];
    const int tid  = threadIdx.x;
    const int wave = tid >> 6, lane = tid & 63;
    const int quad = lane >> 4, l16 = lane & 15;
    const int row0 = blockIdx.x * 16;

    // ---- phase 0: gather-aggregate; one node per 16-lane group ----
    {
        const int ln = wave * 4 + quad;       // local node 0..15
        const int w  = row0 + ln;             // global node (exact fit)
        const int d8 = l16 * 8;               // this lane's 8 dims
        float acc[HEADS][8];
        float z[HEADS];
        {   // self-loop
            const float4 asv = *(const float4*)&as1[w * HEADS];
            const float4 adv = *(const float4*)&ad1[w * HEADS];
            const float ws0 = expf(lrelu(asv.x + adv.x));
            const float ws1 = expf(lrelu(asv.y + adv.y));
            const float ws2 = expf(lrelu(asv.z + adv.z));
            const float ws3 = expf(lrelu(asv.w + adv.w));
            const bf16x8 xv = *(const bf16x8*)&xb[(size_t)w * IN_DIM + d8];
#pragma unroll
            for (int d = 0; d < 8; d++) {
                const float xf = (float)xv[d];
                acc[0][d] = ws0 * xf; acc[1][d] = ws1 * xf;
                acc[2][d] = ws2 * xf; acc[3][d] = ws3 * xf;
            }
            z[0] = ws0; z[1] = ws1; z[2] = ws2; z[3] = ws3;
        }
        const int jb = off[w], je = off[w + 1];
        int j = jb;
        for (; j + 3 < je; j += 4) {
            int    s[4];
            float4 ww[4];
            bf16x8 bv[4];
#pragma unroll
            for (int u = 0; u < 4; u++) s[u] = col[j + u];
#pragma unroll
            for (int u = 0; u < 4; u++) ww[u] = w4[j + u];
#pragma unroll
            for (int u = 0; u < 4; u++)
                bv[u] = *(const bf16x8*)&xb[(size_t)s[u] * IN_DIM + d8];
#pragma unroll
            for (int u = 0; u < 4; u++) {
#pragma unroll
                for (int d = 0; d < 8; d++) {
                    const float xf = (float)bv[u][d];
                    acc[0][d] += ww[u].x * xf;
                    acc[1][d] += ww[u].y * xf;
                    acc[2][d] += ww[u].z * xf;
                    acc[3][d] += ww[u].w * xf;
                }
                z[0] += ww[u].x; z[1] += ww[u].y;
                z[2] += ww[u].z; z[3] += ww[u].w;
            }
        }
        for (; j < je; j++) {
            const int s0 = col[j];
            const float4 w0 = w4[j];
            const bf16x8 b0 = *(const bf16x8*)&xb[(size_t)s0 * IN_DIM + d8];
#pragma unroll
            for (int d = 0; d < 8; d++) {
                const float xf = (float)b0[d];
                acc[0][d] += w0.x * xf; acc[1][d] += w0.y * xf;
                acc[2][d] += w0.z * xf; acc[3][d] += w0.w * xf;
            }
            z[0] += w0.x; z[1] += w0.y; z[2] += w0.z; z[3] += w0.w;
        }
        // normalize + hi/lo split -> LDS (write: 16 lanes x 4 dwords, 2-way)
#pragma unroll
        for (int h = 0; h < HEADS; h++) {
            const float inv = 1.f / z[h];
            bf16x8 hv, lv;
#pragma unroll
            for (int d = 0; d < 8; d++) {
                const float v = acc[h][d] * inv;
                const __bf16 hh = (__bf16)v;
                hv[d] = hh;
                lv[d] = (__bf16)(v - (float)hh);
            }
            const int o = ln * AXS + h * IN_DIM + d8;
            *(bf16x8*)&axh[o] = hv;
            *(bf16x8*)&axl[o] = lv;
        }
    }
    __syncthreads();

    // ---- phase 1: this wave's head = `wave`; A-fragments from LDS ----
    {
        f32x4 acc1[4];
#pragma unroll
        for (int t = 0; t < 4; t++) acc1[t] = (f32x4){0.f, 0.f, 0.f, 0.f};
        const int abase = l16 * AXS + wave * IN_DIM;
#pragma unroll
        for (int kk = 0; kk < 4; kk++) {
            const int k0 = kk * 32 + quad * 8;
            bf16x8 ah = *(const bf16x8*)&axh[abase + k0];
            bf16x8 al = *(const bf16x8*)&axl[abase + k0];
#pragma unroll
            for (int t = 0; t < 4; t++) {
                const size_t bi = (size_t)wave * W1_FRAG +
                                  ((size_t)(t * 4 + kk) * 64 + lane) * 8;
                bf16x8 bhv = *(const bf16x8*)&B1h[bi];
                bf16x8 blv = *(const bf16x8*)&B1l[bi];
                acc1[t] = __builtin_amdgcn_mfma_f32_16x16x32_bf16(ah, bhv, acc1[t], 0, 0, 0);
                acc1[t] = __builtin_amdgcn_mfma_f32_16x16x32_bf16(al, bhv, acc1[t], 0, 0, 0);
                acc1[t] = __builtin_amdgcn_mfma_f32_16x16x32_bf16(ah, blv, acc1[t], 0, 0, 0);
            }
        }
        // ELU(+b1) -> LDS hi/lo planes (split once here, consumed raw below)
#pragma unroll
        for (int t = 0; t < 4; t++) {
            const int c = wave * 64 + t * 16 + l16;
            const float bb = b1[c];
#pragma unroll
            for (int r = 0; r < 4; r++) {
                const float v = eluf(acc1[t][r] + bb);
                const __bf16 hh = (__bf16)v;
                smh[(quad * 4 + r) * LDSB + c] = hh;
                sml[(quad * 4 + r) * LDSB + c] = (__bf16)(v - (float)hh);
            }
        }
    }
    __syncthreads();

    // ---- phase 2: this wave's output cols = tiles {2*wave, 2*wave+1} ----
    f32x4 acc2[2];
#pragma unroll
    for (int t = 0; t < 2; t++) acc2[t] = (f32x4){0.f, 0.f, 0.f, 0.f};
    const int arow = l16 * LDSB;
#pragma unroll
    for (int kk = 0; kk < 8; kk++) {
        const int k0 = kk * 32 + quad * 8;
        bf16x8 ah = *(const bf16x8*)&smh[arow + k0];
        bf16x8 al = *(const bf16x8*)&sml[arow + k0];
#pragma unroll
        for (int tt = 0; tt < 2; tt++) {
            const int t = wave * 2 + tt;
            const size_t bi = ((size_t)(t * 8 + kk) * 64 + lane) * 8;
            bf16x8 bhv = *(const bf16x8*)&B2h[bi];
            bf16x8 blv = *(const bf16x8*)&B2l[bi];
            acc2[tt] = __builtin_amdgcn_mfma_f32_16x16x32_bf16(ah, bhv, acc2[tt], 0, 0, 0);
            acc2[tt] = __builtin_amdgcn_mfma_f32_16x16x32_bf16(al, bhv, acc2[tt], 0, 0, 0);
            acc2[tt] = __builtin_amdgcn_mfma_f32_16x16x32_bf16(ah, blv, acc2[tt], 0, 0, 0);
        }
    }

    // store g2 (bf16) + alpha2 logit partials (f32, exact from acc2)
    const int rowS = row0 + quad * 4;
#pragma unroll
    for (int tt = 0; tt < 2; tt++) {
        const int t = wave * 2 + tt;
#pragma unroll
        for (int r = 0; r < 4; r++) {
            const int rr = rowS + r;
            if (rr < M) g2b[(size_t)rr * EMB + t * 16 + l16] = (__bf16)acc2[tt][r];
        }
    }
#pragma unroll
    for (int r = 0; r < 4; r++) {
        float ps = 0.f, pd = 0.f;
#pragma unroll
        for (int tt = 0; tt < 2; tt++) {
            const int c = (wave * 2 + tt) * 16 + l16;
            ps += acc2[tt][r] * avs[c];
            pd += acc2[tt][r] * avd[c];
        }
#pragma unroll
        for (int o = 1; o < 16; o <<= 1) {
            ps += __shfl_xor(ps, o);
            pd += __shfl_xor(pd, o);
        }
        if (l16 == 0) {
            pps[wave][quad * 4 + r] = ps;
            pdd[wave][quad * 4 + r] = pd;
        }
    }
    __syncthreads();
    if (tid < 16) {
        const int rr = row0 + tid;
        if (rr < M) {
            as_out[rr] = pps[0][tid] + pps[1][tid] + pps[2][tid] + pps[3][tid];
            ad_out[rr] = pdd[0][tid] + pdd[1][tid] + pdd[2][tid] + pdd[3][tid];
        }
    }
}

// ---------------------------------------------------------------------------
// Layer-2 aggregation with INLINE edge weights: ad2[dst] is wave-uniform, so
// w_e = exp(lrelu(as2[col[j]] + ad2w)) computed in-place — kills the w2
// kernel, the w2 buffer (3.2 MB w+r) and rowd (3.2 MB w + scanC fill loop).
// ---------------------------------------------------------------------------
__global__ __launch_bounds__(256) void agg2_kernel(const int* __restrict__ off,
                                                   const int* __restrict__ col,
                                                   const float* __restrict__ as2,
                                                   const float* __restrict__ ad2,
                                                   const __bf16* __restrict__ g2b,
                                                   float* __restrict__ out2, int N) {
    const int w = __builtin_amdgcn_readfirstlane((blockIdx.x * 256 + threadIdx.x) >> 6);
    const int lane = threadIdx.x & 63;
    if (w >= N) return;

    const float ad2w = ad2[w];
    float2 acc = make_float2(0.f, 0.f);
    float z = 0.f;
    {   // self-loop
        const float wt = expf(lrelu(as2[w] + ad2w));
        const bf16x2 hv = *(const bf16x2*)&g2b[(size_t)w * EMB + lane * 2];
        acc.x += wt * (float)hv[0]; acc.y += wt * (float)hv[1];
        z += wt;
    }
    const int jb = off[w], je = off[w + 1];
    int j = jb;
    for (; j + 3 < je; j += 4) {
        const int s0 = col[j], s1 = col[j + 1], s2 = col[j + 2], s3 = col[j + 3];
        const float w0 = expf(lrelu(as2[s0] + ad2w));
        const float w1 = expf(lrelu(as2[s1] + ad2w));
        const float w2v = expf(lrelu(as2[s2] + ad2w));
        const float w3 = expf(lrelu(as2[s3] + ad2w));
        const bf16x2 b0 = *(const bf16x2*)&g2b[(size_t)s0 * EMB + lane * 2];
        const bf16x2 b1 = *(const bf16x2*)&g2b[(size_t)s1 * EMB + lane * 2];
        const bf16x2 b2 = *(const bf16x2*)&g2b[(size_t)s2 * EMB + lane * 2];
        const bf16x2 b3 = *(const bf16x2*)&g2b[(size_t)s3 * EMB + lane * 2];
        acc.x += w0 * (float)b0[0] + w1 * (float)b1[0] + w2v * (float)b2[0] + w3 * (float)b3[0];
        acc.y += w0 * (float)b0[1] + w1 * (float)b1[1] + w2v * (float)b2[1] + w3 * (float)b3[1];
        z += (w0 + w1) + (w2v + w3);
    }
    for (; j < je; j++) {
        const int s0 = col[j];
        const float w0 = expf(lrelu(as2[s0] + ad2w));
        const bf16x2 b0 = *(const bf16x2*)&g2b[(size_t)s0 * EMB + lane * 2];
        acc.x += w0 * (float)b0[0]; acc.y += w0 * (float)b0[1];
        z += w0;
    }
    const float inv = 1.f / z;
    float2 o = make_float2(acc.x * inv, acc.y * inv);
    *(float2*)&out2[(size_t)w * EMB + lane * 2] = o;
}

// ---------------------------------------------------------------------------
// Global mean pool (782-block run-length form) + divide.
// ---------------------------------------------------------------------------
__global__ __launch_bounds__(128) void pool_kernel(const float* __restrict__ out2,
                                                   const float* __restrict__ b2,
                                                   const int* __restrict__ batch,
                                                   float* __restrict__ pool,
                                                   float* __restrict__ cnt, int N) {
    const int c = threadIdx.x;
    const int n0 = blockIdx.x * 64;
    const int nend = min(n0 + 64, N);
    const float bias = b2[c];
    float acc = 0.f, cacc = 0.f;
    int curg = batch[n0];
    for (int n = n0; n < nend; n++) {
        const int g = batch[n];
        if (g != curg) {
            atomicAdd(&pool[curg * EMB + c], acc);
            if (c == 0) atomicAdd(&cnt[curg], cacc);
            acc = 0.f; cacc = 0.f; curg = g;
        }
        float v = out2[(size_t)n * EMB + c] + bias;
        v = v > 0.f ? v : expm1f(v);
        acc += v;
        cacc += 1.f;
    }
    atomicAdd(&pool[curg * EMB + c], acc);
    if (c == 0) atomicAdd(&cnt[curg], cacc);
}

__global__ __launch_bounds__(256) void div_kernel(const float* __restrict__ pool,
                                                  const float* __restrict__ cnt,
                                                  float* __restrict__ out) {
    const int i = blockIdx.x * 256 + threadIdx.x;
    out[i] = pool[i] / fmaxf(cnt[i >> 7], 1.f);
}

// ---------------------------------------------------------------------------
extern "C" void kernel_launch(void* const* d_in, const int* in_sizes, int n_in,
                              void* d_out, int out_size, void* d_ws, size_t ws_size,
                              hipStream_t stream) {
    const float* x      = (const float*)d_in[0];
    const int*   ei     = (const int*)d_in[1];
    const int*   batch  = (const int*)d_in[3];
    const float* W1     = (const float*)d_in[4];
    const float* a_src1 = (const float*)d_in[5];
    const float* a_dst1 = (const float*)d_in[6];
    const float* b1     = (const float*)d_in[7];
    const float* W2     = (const float*)d_in[8];
    const float* a_src2 = (const float*)d_in[9];
    const float* a_dst2 = (const float*)d_in[10];
    const float* b2     = (const float*)d_in[11];
    float* out = (float*)d_out;

    const int N = N_NODES, E = N_EDGES;

    size_t cur_off = 0;
    auto carve = [&](size_t bytes) {
        size_t o = cur_off;
        cur_off = (cur_off + bytes + 255) & ~(size_t)255;
        return (char*)d_ws + o;
    };
    // zero-init region: deg + pool + cnt
    int* deg     = (int*)carve((size_t)N * 4);
    float* pool  = (float*)carve((size_t)N_GRAPHS * EMB * 4);
    float* cnt   = (float*)carve((size_t)N_GRAPHS * 4);
    const size_t zero_bytes = cur_off;
    int* curp    = (int*)carve((size_t)N * 4);
    int* partial = (int*)carve((size_t)SCAN_BLOCKS * 4);
    int* gcur    = (int*)carve((size_t)NBUCK * 4);
    unsigned* stage = (unsigned*)carve((size_t)E * 4);
    __bf16* B1h  = (__bf16*)carve((size_t)HEADS * W1_FRAG * 2);
    __bf16* B1l  = (__bf16*)carve((size_t)HEADS * W1_FRAG * 2);
    __bf16* B2h  = (__bf16*)carve((size_t)F1 * EMB * 2);
    __bf16* B2l  = (__bf16*)carve((size_t)F1 * EMB * 2);
    __bf16* xb   = (__bf16*)carve((size_t)N * IN_DIM * 2);
    int* off     = (int*)carve((size_t)(N + 1) * 4);
    int* col     = (int*)carve((size_t)E * 4);
    float4* w4   = (float4*)carve((size_t)E * 16);
    __bf16* g2b  = (__bf16*)carve((size_t)N * EMB * 2);
    float* out2  = (float*)carve((size_t)N * EMB * 4);
    float* as1   = (float*)carve((size_t)N * HEADS * 4);
    float* ad1   = (float*)carve((size_t)N * HEADS * 4);
    float* as2   = (float*)carve((size_t)N * 4);
    float* ad2   = (float*)carve((size_t)N * 4);

    hipMemsetAsync(d_ws, 0, zero_bytes, stream);

    prep_kernel<<<DEG_BLOCKS + 32 + XCONV_BLOCKS, 256, 0, stream>>>(
        ei, deg, W1, B1h, B1l, W2, B2h, B2l, x, xb);

    scanA_kernel<<<SCAN_BLOCKS, 256, 0, stream>>>(deg, off, partial, N);
    scanB_kernel<<<1, 256, 0, stream>>>(partial, &off[N]);
    scanC_kernel<<<SCAN_BLOCKS, 256, 0, stream>>>(off, partial, curp, gcur, N);

    // gemm1 (x -> as1/ad1) + bucketed edge append (pass 1), one dispatch
    gemm1_scatter_kernel<<<GEMM1_BLOCKS + P1_BLOCKS, 256, 0, stream>>>(
        x, B1h, B1l, a_src1, a_dst1, as1, ad1, N, ei, gcur, stage);

    // pass 2: bucket-local distribution + layer-1 edge weights
    w1s_kernel<<<DEG_BLOCKS, 256, 0, stream>>>(stage, off, curp, as1, ad1, col, w4, E);

    // fused: per-block gather-aggregate -> (@W1 -> ELU -> @W2) + alpha2
    agg_gemm12_kernel<<<AGG12_BLOCKS, 256, 0, stream>>>(off, col, w4, xb, as1, ad1,
                                                        B1h, B1l, b1, B2h, B2l,
                                                        a_src2, a_dst2,
                                                        g2b, as2, ad2, N);

    agg2_kernel<<<(N + 3) / 4, 256, 0, stream>>>(off, col, as2, ad2, g2b, out2, N);

    pool_kernel<<<(N + 63) / 64, 128, 0, stream>>>(out2, b2, batch, pool, cnt, N);
    div_kernel<<<(N_GRAPHS * EMB) / 256, 256, 0, stream>>>(pool, cnt, out);
}

// Round 3
// 337.014 us; speedup vs baseline: 1.0837x; 1.0571x over previous
//
#include <hip/hip_runtime.h>
#include <hip/hip_bf16.h>
#include <cstddef>

// Problem constants (fixed-shape problem)
constexpr int N_NODES = 50000;
constexpr int N_EDGES = 800000;
constexpr int IN_DIM  = 128;
constexpr int HID     = 64;
constexpr int HEADS   = 4;
constexpr int F1      = HEADS * HID;  // 256
constexpr int EMB     = 128;
constexpr int N_GRAPHS = 64;

constexpr int DEG_BLOCKS   = (N_EDGES + 255) / 256;          // 3125
constexpr int SCAN_BLOCKS  = (N_NODES + 255) / 256;          // 196
constexpr int XCONV_BLOCKS = (N_NODES * IN_DIM / 4) / 256;   // 6250 (exact)
// per-head W1 fragment size (NT=4, KK=4): 4*4*64*8 bf16 elements
constexpr int W1_FRAG = 4 * 4 * 64 * 8;                      // 8192
// gemm12 LDS tile stride in bf16 elems: 264*2 = 528 B rows (16 B aligned for
// ds_read_b128; 132 dwords mod 32 = 4 -> ~2-way bank alias, free per m136)
constexpr int LDSB = 264;
// fused-aggregate LDS node-row stride: 4*128+8 elems = 1040 B (16 B aligned,
// 260 dwords mod 32 = 4 -> same mild alias class as LDSB)
constexpr int AXS  = HEADS * IN_DIM + 8;                     // 520
// bucketed CSR build: 256-node buckets, pass-1 appends packed (s|d<<16)
// records per bucket, pass-2 distributes within bucket windows.
constexpr int NBUCK    = (N_NODES + 255) / 256;              // 196
constexpr int P1_CHUNK = 8192;                               // edges per pass-1 block
constexpr int P1_BLOCKS = (N_EDGES + P1_CHUNK - 1) / P1_CHUNK; // 98
constexpr int AS_BLOCKS = N_NODES / 16;                      // 3125 (exact)
constexpr int AGG12_BLOCKS = N_NODES / 16;                   // 3125 (exact)
static_assert(N_NODES % 16 == 0, "16-row tiling assumes exact fit");

typedef __bf16 bf16x8 __attribute__((ext_vector_type(8)));
typedef __bf16 bf16x2 __attribute__((ext_vector_type(2)));
typedef float  f32x4  __attribute__((ext_vector_type(4)));

__device__ __forceinline__ float lrelu(float x) { return x > 0.f ? x : 0.2f * x; }
__device__ __forceinline__ float eluf(float x)  { return x > 0.f ? x : expm1f(x); }

// ---------------------------------------------------------------------------
// Pack a [K x 16*NT] submatrix of B (leading dim ld, origin col0) into
// per-lane MFMA B-fragments, split hi/lo bf16.
// ---------------------------------------------------------------------------
__device__ __forceinline__ void pack_frag(const float* __restrict__ B,
                                          __bf16* __restrict__ hi,
                                          __bf16* __restrict__ lo,
                                          int pblk, int NT, int KK, int ld, int col0) {
    const int gid = pblk * 256 + threadIdx.x;
    if (gid >= NT * KK * 64) return;
    const int lane = gid & 63;
    const int rem  = gid >> 6;
    const int kk   = rem % KK;
    const int t    = rem / KK;
    const int n    = col0 + t * 16 + (lane & 15);
    const int k0   = kk * 32 + (lane >> 4) * 8;
#pragma unroll
    for (int j = 0; j < 8; j++) {
        const float v = B[(size_t)(k0 + j) * ld + n];
        const __bf16 h = (__bf16)v;
        hi[(size_t)gid * 8 + j] = h;
        lo[(size_t)gid * 8 + j] = (__bf16)(v - (float)h);
    }
}

// ---------------------------------------------------------------------------
// prep: [deg histogram | pack W1 | pack W2 | wst = W1^T·a per head | x->bf16]
// wst[8][128]: rows 0..3 = per-head W1·a_src1, rows 4..7 = W1·a_dst1.
// By linearity, alpha-logits are x @ wst^T — replaces the 9.8 GFLOP
// gemm1 with a 102 MFLOP rank-8 projection.
// ---------------------------------------------------------------------------
__global__ __launch_bounds__(256) void prep_kernel(const int* __restrict__ ei,
                                                   int* __restrict__ deg,
                                                   const float* __restrict__ W1,
                                                   __bf16* __restrict__ B1h,
                                                   __bf16* __restrict__ B1l,
                                                   const float* __restrict__ W2,
                                                   __bf16* __restrict__ B2h,
                                                   __bf16* __restrict__ B2l,
                                                   const float* __restrict__ as1v,
                                                   const float* __restrict__ ad1v,
                                                   float* __restrict__ wst,
                                                   const float* __restrict__ x,
                                                   __bf16* __restrict__ xb) {
    const int b = blockIdx.x;
    if (b < DEG_BLOCKS) {
        const int e = b * 256 + threadIdx.x;
        if (e < N_EDGES) atomicAdd(&deg[ei[N_EDGES + e]], 1);
        return;
    }
    const int pb = b - DEG_BLOCKS;
    if (pb < 16) {
        const int head = pb >> 2;
        pack_frag(W1, B1h + head * W1_FRAG, B1l + head * W1_FRAG,
                  pb & 3, 4, 4, F1, head * HID);
        return;
    }
    if (pb < 32) {
        pack_frag(W2, B2h, B2l, pb - 16, 8, 8, EMB, 0);
        return;
    }
    if (pb < 36) {
        // wst[o][c] = sum_k W1[c][h*64+k] * a[h][k], o = (src?0:4)+h
        const int gid = (pb - 32) * 256 + threadIdx.x;  // 0..1023
        const int o = gid >> 7, c = gid & 127;
        const int h = o & 3;
        const float* av = (o < 4) ? as1v : ad1v;
        float s = 0.f;
#pragma unroll 8
        for (int k = 0; k < HID; k++)
            s += W1[(size_t)c * F1 + h * HID + k] * av[h * HID + k];
        wst[o * IN_DIM + c] = s;
        return;
    }
    // x -> bf16 (float4 in, 4x bf16 out)
    const int i = (pb - 36) * 256 + threadIdx.x;  // quad index
    const float4 v = *(const float4*)&x[(size_t)i * 4];
    __bf16 o[4] = {(__bf16)v.x, (__bf16)v.y, (__bf16)v.z, (__bf16)v.w};
    *(ulong1*)&xb[(size_t)i * 4] = *(ulong1*)o;
}

// ---------------------------------------------------------------------------
// 3-phase parallel scan (deg -> off). Phase C also zeroes cur and seeds the
// per-bucket append cursors gcur[b] = off[b*256].
// ---------------------------------------------------------------------------
__global__ __launch_bounds__(256) void scanA_kernel(const int* __restrict__ deg,
                                                    int* __restrict__ off,
                                                    int* __restrict__ partial, int N) {
    __shared__ int sm[256];
    const int t = threadIdx.x;
    const int i = blockIdx.x * 256 + t;
    const int v = (i < N) ? deg[i] : 0;
    sm[t] = v;
    __syncthreads();
    int val = v;
#pragma unroll
    for (int o = 1; o < 256; o <<= 1) {
        const int add = (t >= o) ? sm[t - o] : 0;
        __syncthreads();
        val += add;
        sm[t] = val;
        __syncthreads();
    }
    if (i < N) off[i] = val - v;
    if (t == 255) partial[blockIdx.x] = val;
}

__global__ __launch_bounds__(256) void scanB_kernel(int* __restrict__ partial,
                                                    int* __restrict__ off_last) {
    __shared__ int sm[256];
    const int t = threadIdx.x;
    const int v = (t < SCAN_BLOCKS) ? partial[t] : 0;
    sm[t] = v;
    __syncthreads();
    int val = v;
#pragma unroll
    for (int o = 1; o < 256; o <<= 1) {
        const int add = (t >= o) ? sm[t - o] : 0;
        __syncthreads();
        val += add;
        sm[t] = val;
        __syncthreads();
    }
    if (t < SCAN_BLOCKS) partial[t] = val - v;
    if (t == SCAN_BLOCKS - 1) *off_last = val;
}

__global__ __launch_bounds__(256) void scanC_kernel(int* __restrict__ off,
                                                    const int* __restrict__ partial,
                                                    int* __restrict__ cur,
                                                    int* __restrict__ gcur, int N) {
    const int i = blockIdx.x * 256 + threadIdx.x;
    if (i < N) {
        const int o = off[i] + partial[blockIdx.x];
        off[i] = o;
        cur[i] = 0;
        if ((i & 255) == 0) gcur[i >> 8] = o;   // bucket append cursor
    }
}

// ---------------------------------------------------------------------------
// as_scatter: [rank-8 logit projection | pass-1 bucketed edge append].
// Logits: one node per 16-lane group; lane covers 8 dims (2x float4);
// wst rows are coalesced 32 B runs, L1/L2-resident (4 KB total).
// ---------------------------------------------------------------------------
__global__ __launch_bounds__(256) void as_scatter_kernel(
        const float* __restrict__ x, const float* __restrict__ wst,
        float* __restrict__ as_out, float* __restrict__ ad_out,
        const int* __restrict__ ei, int* __restrict__ gcur,
        unsigned* __restrict__ stage) {
    const int tid = threadIdx.x;
    if (blockIdx.x < AS_BLOCKS) {
        const int n   = blockIdx.x * 16 + (tid >> 4);
        const int l16 = tid & 15;
        const int d8  = l16 * 8;
        const float4 xa = *(const float4*)&x[(size_t)n * IN_DIM + d8];
        const float4 xc = *(const float4*)&x[(size_t)n * IN_DIM + d8 + 4];
        float p[8];
#pragma unroll
        for (int o = 0; o < 8; o++) {
            const float4 wa = *(const float4*)&wst[o * IN_DIM + d8];
            const float4 wb = *(const float4*)&wst[o * IN_DIM + d8 + 4];
            p[o] = xa.x * wa.x + xa.y * wa.y + xa.z * wa.z + xa.w * wa.w
                 + xc.x * wb.x + xc.y * wb.y + xc.z * wb.z + xc.w * wb.w;
        }
#pragma unroll
        for (int off = 1; off < 16; off <<= 1) {
#pragma unroll
            for (int o = 0; o < 8; o++) p[o] += __shfl_xor(p[o], off);
        }
        if (l16 == 0) {
            *(float4*)&as_out[n * HEADS] = (float4){p[0], p[1], p[2], p[3]};
            *(float4*)&ad_out[n * HEADS] = (float4){p[4], p[5], p[6], p[7]};
        }
        return;
    }
    // pass-1 bucketed append
    __shared__ int lhist[NBUCK];
    __shared__ int lbase[NBUCK];
    const int e0 = (blockIdx.x - AS_BLOCKS) * P1_CHUNK;
    for (int b = tid; b < NBUCK; b += 256) lhist[b] = 0;
    __syncthreads();
    for (int i = 0; i < P1_CHUNK / 256; i++) {
        const int e = e0 + i * 256 + tid;
        if (e < N_EDGES) atomicAdd(&lhist[ei[N_EDGES + e] >> 8], 1);
    }
    __syncthreads();
    for (int b = tid; b < NBUCK; b += 256) {
        const int c = lhist[b];
        lbase[b] = c ? atomicAdd(&gcur[b], c) : 0;
    }
    __syncthreads();
    for (int b = tid; b < NBUCK; b += 256) lhist[b] = 0;
    __syncthreads();
    for (int i = 0; i < P1_CHUNK / 256; i++) {
        const int e = e0 + i * 256 + tid;
        if (e < N_EDGES) {
            const int s = ei[e], d = ei[N_EDGES + e];
            const int bk = d >> 8;
            const int r  = atomicAdd(&lhist[bk], 1);
            stage[lbase[bk] + r] = (unsigned)s | ((unsigned)d << 16);
        }
    }
}

// Pass 2: read bucket-grouped stage linearly, distribute within the bucket's
// small col/w4 windows (L2-hot), and compute the layer-1 edge weights.
__global__ __launch_bounds__(256) void w1s_kernel(const unsigned* __restrict__ stage,
                                                  const int* __restrict__ off,
                                                  int* __restrict__ cur,
                                                  const float* __restrict__ as1,
                                                  const float* __restrict__ ad1,
                                                  int* __restrict__ col,
                                                  float4* __restrict__ w4, int E) {
    const int i = blockIdx.x * 256 + threadIdx.x;
    if (i >= E) return;
    const unsigned p = stage[i];
    const int s = (int)(p & 0xFFFFu);
    const int d = (int)(p >> 16);
    const float4 a = *(const float4*)&as1[s * HEADS];
    const float4 b = *(const float4*)&ad1[d * HEADS];
    const int pos = off[d] + atomicAdd(&cur[d], 1);
    float4 o;
    o.x = expf(lrelu(a.x + b.x));
    o.y = expf(lrelu(a.y + b.y));
    o.z = expf(lrelu(a.z + b.z));
    o.w = expf(lrelu(a.w + b.w));
    col[pos] = s;
    w4[pos] = o;
}

// ---------------------------------------------------------------------------
// FUSED layer-1 aggregation + layer-1 GEMM + layer-2 GEMM, 16 rows/block.
// LDS: the inter-layer smh/sml tile ALIASES the axh/axl gather planes
// (phase 1 preloads its A-fragments to registers, barriers, then overwrites)
// -> 33.8 KB total -> 4 blocks/CU (was 50.7 KB / 3 blocks).
// ---------------------------------------------------------------------------
__global__ __launch_bounds__(256, 4) void agg_gemm12_kernel(
        const int* __restrict__ off, const int* __restrict__ col,
        const float4* __restrict__ w4, const __bf16* __restrict__ xb,
        const float* __restrict__ as1, const float* __restrict__ ad1,
        const __bf16* __restrict__ B1h, const __bf16* __restrict__ B1l,
        const float* __restrict__ b1,
        const __bf16* __restrict__ B2h, const __bf16* __restrict__ B2l,
        const float* __restrict__ avs, const float* __restrict__ avd,
        __bf16* __restrict__ g2b, float* __restrict__ as_out,
        float* __restrict__ ad_out, int M) {
    __shared__ __bf16 axh[16 * AXS];          // 16.25 KB (smh aliases)
    __shared__ __bf16 axl[16 * AXS];          // 16.25 KB (sml aliases)
    __shared__ float pps[4][16], pdd[4][16];
    __bf16* const smh = axh;
    __bf16* const sml = axl;
    const int tid  = threadIdx.x;
    const int wave = tid >> 6, lane = tid & 63;
    const int quad = lane >> 4, l16 = lane & 15;
    const int row0 = blockIdx.x * 16;

    // ---- phase 0: gather-aggregate; one node per 16-lane group ----
    {
        const int ln = wave * 4 + quad;       // local node 0..15
        const int w  = row0 + ln;             // global node (exact fit)
        const int d8 = l16 * 8;               // this lane's 8 dims
        float acc[HEADS][8];
        float z[HEADS];
        {   // self-loop
            const float4 asv = *(const float4*)&as1[w * HEADS];
            const float4 adv = *(const float4*)&ad1[w * HEADS];
            const float ws0 = expf(lrelu(asv.x + adv.x));
            const float ws1 = expf(lrelu(asv.y + adv.y));
            const float ws2 = expf(lrelu(asv.z + adv.z));
            const float ws3 = expf(lrelu(asv.w + adv.w));
            const bf16x8 xv = *(const bf16x8*)&xb[(size_t)w * IN_DIM + d8];
#pragma unroll
            for (int d = 0; d < 8; d++) {
                const float xf = (float)xv[d];
                acc[0][d] = ws0 * xf; acc[1][d] = ws1 * xf;
                acc[2][d] = ws2 * xf; acc[3][d] = ws3 * xf;
            }
            z[0] = ws0; z[1] = ws1; z[2] = ws2; z[3] = ws3;
        }
        const int jb = off[w], je = off[w + 1];
        int j = jb;
        for (; j + 3 < je; j += 4) {
            int    s[4];
            float4 ww[4];
            bf16x8 bv[4];
#pragma unroll
            for (int u = 0; u < 4; u++) s[u] = col[j + u];
#pragma unroll
            for (int u = 0; u < 4; u++) ww[u] = w4[j + u];
#pragma unroll
            for (int u = 0; u < 4; u++)
                bv[u] = *(const bf16x8*)&xb[(size_t)s[u] * IN_DIM + d8];
#pragma unroll
            for (int u = 0; u < 4; u++) {
#pragma unroll
                for (int d = 0; d < 8; d++) {
                    const float xf = (float)bv[u][d];
                    acc[0][d] += ww[u].x * xf;
                    acc[1][d] += ww[u].y * xf;
                    acc[2][d] += ww[u].z * xf;
                    acc[3][d] += ww[u].w * xf;
                }
                z[0] += ww[u].x; z[1] += ww[u].y;
                z[2] += ww[u].z; z[3] += ww[u].w;
            }
        }
        for (; j < je; j++) {
            const int s0 = col[j];
            const float4 w0 = w4[j];
            const bf16x8 b0 = *(const bf16x8*)&xb[(size_t)s0 * IN_DIM + d8];
#pragma unroll
            for (int d = 0; d < 8; d++) {
                const float xf = (float)b0[d];
                acc[0][d] += w0.x * xf; acc[1][d] += w0.y * xf;
                acc[2][d] += w0.z * xf; acc[3][d] += w0.w * xf;
            }
            z[0] += w0.x; z[1] += w0.y; z[2] += w0.z; z[3] += w0.w;
        }
        // normalize + hi/lo split -> LDS
#pragma unroll
        for (int h = 0; h < HEADS; h++) {
            const float inv = 1.f / z[h];
            bf16x8 hv, lv;
#pragma unroll
            for (int d = 0; d < 8; d++) {
                const float v = acc[h][d] * inv;
                const __bf16 hh = (__bf16)v;
                hv[d] = hh;
                lv[d] = (__bf16)(v - (float)hh);
            }
            const int o = ln * AXS + h * IN_DIM + d8;
            *(bf16x8*)&axh[o] = hv;
            *(bf16x8*)&axl[o] = lv;
        }
    }
    __syncthreads();

    // ---- phase 1: this wave's head = `wave`; A-fragments -> regs, then
    // barrier, then MFMA + ELU write into the ALIASED smh/sml region ----
    {
        bf16x8 ahv[4], alv[4];
        const int abase = l16 * AXS + wave * IN_DIM;
#pragma unroll
        for (int kk = 0; kk < 4; kk++) {
            const int k0 = kk * 32 + quad * 8;
            ahv[kk] = *(const bf16x8*)&axh[abase + k0];
            alv[kk] = *(const bf16x8*)&axl[abase + k0];
        }
        __syncthreads();   // all ax reads complete before alias overwrite

        f32x4 acc1[4];
#pragma unroll
        for (int t = 0; t < 4; t++) acc1[t] = (f32x4){0.f, 0.f, 0.f, 0.f};
#pragma unroll
        for (int kk = 0; kk < 4; kk++) {
#pragma unroll
            for (int t = 0; t < 4; t++) {
                const size_t bi = (size_t)wave * W1_FRAG +
                                  ((size_t)(t * 4 + kk) * 64 + lane) * 8;
                bf16x8 bhv = *(const bf16x8*)&B1h[bi];
                bf16x8 blv = *(const bf16x8*)&B1l[bi];
                acc1[t] = __builtin_amdgcn_mfma_f32_16x16x32_bf16(ahv[kk], bhv, acc1[t], 0, 0, 0);
                acc1[t] = __builtin_amdgcn_mfma_f32_16x16x32_bf16(alv[kk], bhv, acc1[t], 0, 0, 0);
                acc1[t] = __builtin_amdgcn_mfma_f32_16x16x32_bf16(ahv[kk], blv, acc1[t], 0, 0, 0);
            }
        }
        // ELU(+b1) -> aliased LDS hi/lo planes
#pragma unroll
        for (int t = 0; t < 4; t++) {
            const int c = wave * 64 + t * 16 + l16;
            const float bb = b1[c];
#pragma unroll
            for (int r = 0; r < 4; r++) {
                const float v = eluf(acc1[t][r] + bb);
                const __bf16 hh = (__bf16)v;
                smh[(quad * 4 + r) * LDSB + c] = hh;
                sml[(quad * 4 + r) * LDSB + c] = (__bf16)(v - (float)hh);
            }
        }
    }
    __syncthreads();

    // ---- phase 2: this wave's output cols = tiles {2*wave, 2*wave+1} ----
    f32x4 acc2[2];
#pragma unroll
    for (int t = 0; t < 2; t++) acc2[t] = (f32x4){0.f, 0.f, 0.f, 0.f};
    const int arow = l16 * LDSB;
#pragma unroll
    for (int kk = 0; kk < 8; kk++) {
        const int k0 = kk * 32 + quad * 8;
        bf16x8 ah = *(const bf16x8*)&smh[arow + k0];
        bf16x8 al = *(const bf16x8*)&sml[arow + k0];
#pragma unroll
        for (int tt = 0; tt < 2; tt++) {
            const int t = wave * 2 + tt;
            const size_t bi = ((size_t)(t * 8 + kk) * 64 + lane) * 8;
            bf16x8 bhv = *(const bf16x8*)&B2h[bi];
            bf16x8 blv = *(const bf16x8*)&B2l[bi];
            acc2[tt] = __builtin_amdgcn_mfma_f32_16x16x32_bf16(ah, bhv, acc2[tt], 0, 0, 0);
            acc2[tt] = __builtin_amdgcn_mfma_f32_16x16x32_bf16(al, bhv, acc2[tt], 0, 0, 0);
            acc2[tt] = __builtin_amdgcn_mfma_f32_16x16x32_bf16(ah, blv, acc2[tt], 0, 0, 0);
        }
    }

    // store g2 (bf16) + alpha2 logit partials (f32, exact from acc2)
    const int rowS = row0 + quad * 4;
#pragma unroll
    for (int tt = 0; tt < 2; tt++) {
        const int t = wave * 2 + tt;
#pragma unroll
        for (int r = 0; r < 4; r++) {
            const int rr = rowS + r;
            if (rr < M) g2b[(size_t)rr * EMB + t * 16 + l16] = (__bf16)acc2[tt][r];
        }
    }
#pragma unroll
    for (int r = 0; r < 4; r++) {
        float ps = 0.f, pd = 0.f;
#pragma unroll
        for (int tt = 0; tt < 2; tt++) {
            const int c = (wave * 2 + tt) * 16 + l16;
            ps += acc2[tt][r] * avs[c];
            pd += acc2[tt][r] * avd[c];
        }
#pragma unroll
        for (int o = 1; o < 16; o <<= 1) {
            ps += __shfl_xor(ps, o);
            pd += __shfl_xor(pd, o);
        }
        if (l16 == 0) {
            pps[wave][quad * 4 + r] = ps;
            pdd[wave][quad * 4 + r] = pd;
        }
    }
    __syncthreads();
    if (tid < 16) {
        const int rr = row0 + tid;
        if (rr < M) {
            as_out[rr] = pps[0][tid] + pps[1][tid] + pps[2][tid] + pps[3][tid];
            ad_out[rr] = pdd[0][tid] + pdd[1][tid] + pdd[2][tid] + pdd[3][tid];
        }
    }
}

// ---------------------------------------------------------------------------
// Layer-2 aggregation with inline edge weights (ad2[dst] wave-uniform).
// ---------------------------------------------------------------------------
__global__ __launch_bounds__(256) void agg2_kernel(const int* __restrict__ off,
                                                   const int* __restrict__ col,
                                                   const float* __restrict__ as2,
                                                   const float* __restrict__ ad2,
                                                   const __bf16* __restrict__ g2b,
                                                   float* __restrict__ out2, int N) {
    const int w = __builtin_amdgcn_readfirstlane((blockIdx.x * 256 + threadIdx.x) >> 6);
    const int lane = threadIdx.x & 63;
    if (w >= N) return;

    const float ad2w = ad2[w];
    float2 acc = make_float2(0.f, 0.f);
    float z = 0.f;
    {   // self-loop
        const float wt = expf(lrelu(as2[w] + ad2w));
        const bf16x2 hv = *(const bf16x2*)&g2b[(size_t)w * EMB + lane * 2];
        acc.x += wt * (float)hv[0]; acc.y += wt * (float)hv[1];
        z += wt;
    }
    const int jb = off[w], je = off[w + 1];
    int j = jb;
    for (; j + 3 < je; j += 4) {
        const int s0 = col[j], s1 = col[j + 1], s2 = col[j + 2], s3 = col[j + 3];
        const float w0 = expf(lrelu(as2[s0] + ad2w));
        const float w1 = expf(lrelu(as2[s1] + ad2w));
        const float w2v = expf(lrelu(as2[s2] + ad2w));
        const float w3 = expf(lrelu(as2[s3] + ad2w));
        const bf16x2 b0 = *(const bf16x2*)&g2b[(size_t)s0 * EMB + lane * 2];
        const bf16x2 b1 = *(const bf16x2*)&g2b[(size_t)s1 * EMB + lane * 2];
        const bf16x2 b2 = *(const bf16x2*)&g2b[(size_t)s2 * EMB + lane * 2];
        const bf16x2 b3 = *(const bf16x2*)&g2b[(size_t)s3 * EMB + lane * 2];
        acc.x += w0 * (float)b0[0] + w1 * (float)b1[0] + w2v * (float)b2[0] + w3 * (float)b3[0];
        acc.y += w0 * (float)b0[1] + w1 * (float)b1[1] + w2v * (float)b2[1] + w3 * (float)b3[1];
        z += (w0 + w1) + (w2v + w3);
    }
    for (; j < je; j++) {
        const int s0 = col[j];
        const float w0 = expf(lrelu(as2[s0] + ad2w));
        const bf16x2 b0 = *(const bf16x2*)&g2b[(size_t)s0 * EMB + lane * 2];
        acc.x += w0 * (float)b0[0]; acc.y += w0 * (float)b0[1];
        z += w0;
    }
    const float inv = 1.f / z;
    float2 o = make_float2(acc.x * inv, acc.y * inv);
    *(float2*)&out2[(size_t)w * EMB + lane * 2] = o;
}

// ---------------------------------------------------------------------------
// Global mean pool (run-length form) + divide.
// ---------------------------------------------------------------------------
__global__ __launch_bounds__(128) void pool_kernel(const float* __restrict__ out2,
                                                   const float* __restrict__ b2,
                                                   const int* __restrict__ batch,
                                                   float* __restrict__ pool,
                                                   float* __restrict__ cnt, int N) {
    const int c = threadIdx.x;
    const int n0 = blockIdx.x * 64;
    const int nend = min(n0 + 64, N);
    const float bias = b2[c];
    float acc = 0.f, cacc = 0.f;
    int curg = batch[n0];
    for (int n = n0; n < nend; n++) {
        const int g = batch[n];
        if (g != curg) {
            atomicAdd(&pool[curg * EMB + c], acc);
            if (c == 0) atomicAdd(&cnt[curg], cacc);
            acc = 0.f; cacc = 0.f; curg = g;
        }
        float v = out2[(size_t)n * EMB + c] + bias;
        v = v > 0.f ? v : expm1f(v);
        acc += v;
        cacc += 1.f;
    }
    atomicAdd(&pool[curg * EMB + c], acc);
    if (c == 0) atomicAdd(&cnt[curg], cacc);
}

__global__ __launch_bounds__(256) void div_kernel(const float* __restrict__ pool,
                                                  const float* __restrict__ cnt,
                                                  float* __restrict__ out) {
    const int i = blockIdx.x * 256 + threadIdx.x;
    out[i] = pool[i] / fmaxf(cnt[i >> 7], 1.f);
}

// ---------------------------------------------------------------------------
extern "C" void kernel_launch(void* const* d_in, const int* in_sizes, int n_in,
                              void* d_out, int out_size, void* d_ws, size_t ws_size,
                              hipStream_t stream) {
    const float* x      = (const float*)d_in[0];
    const int*   ei     = (const int*)d_in[1];
    const int*   batch  = (const int*)d_in[3];
    const float* W1     = (const float*)d_in[4];
    const float* a_src1 = (const float*)d_in[5];
    const float* a_dst1 = (const float*)d_in[6];
    const float* b1     = (const float*)d_in[7];
    const float* W2     = (const float*)d_in[8];
    const float* a_src2 = (const float*)d_in[9];
    const float* a_dst2 = (const float*)d_in[10];
    const float* b2     = (const float*)d_in[11];
    float* out = (float*)d_out;

    const int N = N_NODES, E = N_EDGES;

    size_t cur_off = 0;
    auto carve = [&](size_t bytes) {
        size_t o = cur_off;
        cur_off = (cur_off + bytes + 255) & ~(size_t)255;
        return (char*)d_ws + o;
    };
    // zero-init region: deg + pool + cnt
    int* deg     = (int*)carve((size_t)N * 4);
    float* pool  = (float*)carve((size_t)N_GRAPHS * EMB * 4);
    float* cnt   = (float*)carve((size_t)N_GRAPHS * 4);
    const size_t zero_bytes = cur_off;
    int* curp    = (int*)carve((size_t)N * 4);
    int* partial = (int*)carve((size_t)SCAN_BLOCKS * 4);
    int* gcur    = (int*)carve((size_t)NBUCK * 4);
    unsigned* stage = (unsigned*)carve((size_t)E * 4);
    float* wst   = (float*)carve((size_t)8 * IN_DIM * 4);
    __bf16* B1h  = (__bf16*)carve((size_t)HEADS * W1_FRAG * 2);
    __bf16* B1l  = (__bf16*)carve((size_t)HEADS * W1_FRAG * 2);
    __bf16* B2h  = (__bf16*)carve((size_t)F1 * EMB * 2);
    __bf16* B2l  = (__bf16*)carve((size_t)F1 * EMB * 2);
    __bf16* xb   = (__bf16*)carve((size_t)N * IN_DIM * 2);
    int* off     = (int*)carve((size_t)(N + 1) * 4);
    int* col     = (int*)carve((size_t)E * 4);
    float4* w4   = (float4*)carve((size_t)E * 16);
    __bf16* g2b  = (__bf16*)carve((size_t)N * EMB * 2);
    float* out2  = (float*)carve((size_t)N * EMB * 4);
    float* as1   = (float*)carve((size_t)N * HEADS * 4);
    float* ad1   = (float*)carve((size_t)N * HEADS * 4);
    float* as2   = (float*)carve((size_t)N * 4);
    float* ad2   = (float*)carve((size_t)N * 4);

    hipMemsetAsync(d_ws, 0, zero_bytes, stream);

    prep_kernel<<<DEG_BLOCKS + 36 + XCONV_BLOCKS, 256, 0, stream>>>(
        ei, deg, W1, B1h, B1l, W2, B2h, B2l, a_src1, a_dst1, wst, x, xb);

    scanA_kernel<<<SCAN_BLOCKS, 256, 0, stream>>>(deg, off, partial, N);
    scanB_kernel<<<1, 256, 0, stream>>>(partial, &off[N]);
    scanC_kernel<<<SCAN_BLOCKS, 256, 0, stream>>>(off, partial, curp, gcur, N);

    // rank-8 logit projection (x -> as1/ad1) + bucketed edge append (pass 1)
    as_scatter_kernel<<<AS_BLOCKS + P1_BLOCKS, 256, 0, stream>>>(
        x, wst, as1, ad1, ei, gcur, stage);

    // pass 2: bucket-local distribution + layer-1 edge weights
    w1s_kernel<<<DEG_BLOCKS, 256, 0, stream>>>(stage, off, curp, as1, ad1, col, w4, E);

    // fused: per-block gather-aggregate -> (@W1 -> ELU -> @W2) + alpha2
    agg_gemm12_kernel<<<AGG12_BLOCKS, 256, 0, stream>>>(off, col, w4, xb, as1, ad1,
                                                        B1h, B1l, b1, B2h, B2l,
                                                        a_src2, a_dst2,
                                                        g2b, as2, ad2, N);

    agg2_kernel<<<(N + 3) / 4, 256, 0, stream>>>(off, col, as2, ad2, g2b, out2, N);

    pool_kernel<<<(N + 63) / 64, 128, 0, stream>>>(out2, b2, batch, pool, cnt, N);
    div_kernel<<<(N_GRAPHS * EMB) / 256, 256, 0, stream>>>(pool, cnt, out);
}